// Round 7
// baseline (532.316 us; speedup 1.0000x reference)
//
#include <hip/hip_runtime.h>

#define N_NODES 50000
#define E_EDGES 262144

typedef __attribute__((ext_vector_type(8))) _Float16 f16x8;
typedef __attribute__((ext_vector_type(2))) _Float16 f16x2;
typedef __attribute__((ext_vector_type(4))) float f32x4;

union V16 { uint4 u; f16x8 h; };
union U32 { unsigned u; f16x2 p; };

// pack two f32 -> two f16 (RNE), a in low half
__device__ __forceinline__ unsigned h2pack(float a, float b) {
  union { _Float16 h[2]; unsigned u; } r;
  r.h[0] = (_Float16)a;
  r.h[1] = (_Float16)b;
  return r.u;
}
__device__ __forceinline__ void async_gather16(const void* gptr, void* lptr) {
  __builtin_amdgcn_global_load_lds(
      (const __attribute__((address_space(1))) void*)gptr,
      (__attribute__((address_space(3))) void*)lptr, 16, 0, 0);
}

// ---- prep: node_repr fp32 -> fp16 (RNE) ----
__global__ void cvt_node_kernel(const float* __restrict__ x, unsigned short* __restrict__ y) {
  int i = (blockIdx.x * 256 + threadIdx.x) * 8;
  float4 f0 = *(const float4*)(x + i);
  float4 f1 = *(const float4*)(x + i + 4);
  uint4 o;
  o.x = h2pack(f0.x, f0.y);
  o.y = h2pack(f0.z, f0.w);
  o.z = h2pack(f1.x, f1.y);
  o.w = h2pack(f1.z, f1.w);
  *(uint4*)(y + i) = o;
}

// ---- prep: W1 (1024x512 row-major in->out) -> W1pp2 fp16, 16-B units laid out
// [step(8)][sq=s*4+quad(16)][col(512)], unit = W1[k0..k0+8)[col], k0=s*256+step*32+quad*8
__global__ void prep_w1pp2_kernel(const float* __restrict__ w1, unsigned short* __restrict__ w1pp2) {
  int t = blockIdx.x * 256 + threadIdx.x;  // 65536 units
  int step = t >> 13;
  int rem = t & 8191;
  int sq = rem >> 9;
  int col = rem & 511;
  int s = sq >> 2, qd = sq & 3;
  int k0 = s * 256 + step * 32 + qd * 8;
  float f[8];
#pragma unroll
  for (int i = 0; i < 8; ++i) f[i] = w1[(size_t)(k0 + i) * 512 + col];
  uint4 o;
  o.x = h2pack(f[0], f[1]);
  o.y = h2pack(f[2], f[3]);
  o.z = h2pack(f[4], f[5]);
  o.w = h2pack(f[6], f[7]);
  *(uint4*)(w1pp2 + (size_t)t * 8) = o;
}

// ---- prep: out[e][c] = b2[c] ----
__global__ void init_out_kernel(float* __restrict__ out, const float* __restrict__ b2) {
  int i = blockIdx.x * 256 + threadIdx.x;
  float2 v; v.x = b2[0]; v.y = b2[1];
  *(float2*)(out + (size_t)i * 2) = v;
}

// ---- main fused kernel R7: block = 64 edges x 128 cols, wave = 64e x 32c.
//      WHY: occupancy is quantized by TOTAL regs (VGPR+AGPR) at 64/128/256 ->
//      8/4/2 waves per SIMD. All prior clean versions: acc[4][4]=64 AGPR + ~100
//      arch = ~160-190 total -> 2 waves/SIMD -> every pipe idles at ~33%
//      (latency-bound, R5/R6 proved neither VALU count nor prefetch moves it).
//      This version: acc[4][2]=32 AGPR + ~90 arch ~= 122 <= 128 -> 4 waves/SIMD.
//      LDS: R4's verified 2-chunk A staging (32 KB) -> 4 blocks/CU fit (128 KB).
//      Grid 16384 (4 col-quarter blocks per 64-edge tile); B L2 traffic unchanged.
//      NO second __launch_bounds__ arg (forces VGPR=64 -> spill catastrophe). ----
__global__ __launch_bounds__(256) void edge_mlp_kernel(
    const unsigned short* __restrict__ nodeb,  // [50000][256] fp16
    const unsigned short* __restrict__ w1pp2,  // repacked W1 (see prep)
    const int* __restrict__ src,
    const int* __restrict__ dst,
    const float* __restrict__ b1,
    const float* __restrict__ w2,   // [512][2] fp32
    float* __restrict__ out) {      // [E][2] fp32, pre-init with b2
  // Per chunk: hi: [0,16K) — 64 edges x 256 B; hj: [16K,32K)
  __shared__ char smem[32768];

  const int tid = threadIdx.x;
  const int wid = tid >> 6;      // 0..3
  const int lane = tid & 63;
  const int quad = lane >> 4;
  const int l16 = lane & 15;
  const int bx = blockIdx.x;     // 0..16383
  // XCD swizzle: xc = bx&7; col-sibling + neighbor m-tiles share an XCD
  const int xc = bx & 7;
  const int t2 = bx >> 3;
  const int n_quarter = t2 & 3;              // 0..3 (128-col quarters)
  const int m_idx = (t2 >> 2) * 8 + xc;      // 0..4095 (64-edge tiles)
  const int row0 = m_idx * 64;
  const int n0 = n_quarter * 128 + wid * 32;

  const char* nodeB = (const char*)nodeb;
  const char* w1B = (const char*)w1pp2;

  // ---- B register-load offsets: (s*4+quad)*8192 + (n0+l16)*16 (+ step*131072) ----
  unsigned bOff[4];
#pragma unroll
  for (int s = 0; s < 4; ++s)
    bOff[s] = (unsigned)((s * 4 + quad) * 8192 + (n0 + l16) * 16);
  const char* w1s = w1B;

  // ---- A reader base: byte = (mt*16+l16)*256 + (((st4*4+q)^(l16&7))<<4) ----
  const unsigned aXor = (unsigned)(l16 & 7);
  const unsigned aBase = (unsigned)(l16 * 256);

  f32x4 acc[4][2];
#pragma unroll
  for (int mt = 0; mt < 4; ++mt)
#pragma unroll
    for (int nt = 0; nt < 2; ++nt)
      acc[mt][nt] = (f32x4){0.f, 0.f, 0.f, 0.f};

  // ---- chunked A staging (verified in R4): chunk ck stages bytes
  //      [ck*256, ck*256+256) of each gathered node row. Linear LDS dest;
  //      XOR swizzle carried on the SOURCE address. ----
  auto stage_chunk = [&](int ck) {
    const int eh = tid >> 4;  // 0..15
    const unsigned wsw = (unsigned)(((tid & 15) ^ (eh & 7)) << 4) + (unsigned)(ck * 256);
#pragma unroll
    for (int c = 0; c < 4; ++c) {
      int e = c * 16 + eh;
      unsigned so = ((unsigned)src[row0 + e] << 9) + wsw;
      unsigned do_ = ((unsigned)dst[row0 + e] << 9) + wsw;
      async_gather16(nodeB + so, smem + c * 4096 + wid * 1024);
      async_gather16(nodeB + do_, smem + 16384 + c * 4096 + wid * 1024);
    }
  };

  // ---- one K-step (in-chunk index st4 = 0..3) ----
  auto kstep = [&](int st4) {
    V16 bf[4][2];
#pragma unroll
    for (int s = 0; s < 4; ++s)
#pragma unroll
      for (int nt = 0; nt < 2; ++nt)
        bf[s][nt].u = *(const uint4*)(w1s + bOff[s] + nt * 256);
    const unsigned stq = (unsigned)(st4 * 4 + quad);
    V16 hi[4], hj[4];
#pragma unroll
    for (int mt = 0; mt < 4; ++mt) {
      unsigned ao = (unsigned)(mt * 16 * 256) + aBase + ((stq ^ aXor) << 4);
      hi[mt].u = *(const uint4*)(smem + ao);
      hj[mt].u = *(const uint4*)(smem + 16384 + ao);
    }
    // MFMA s=0 (hi), s=1 (hj)
#pragma unroll
    for (int mt = 0; mt < 4; ++mt)
#pragma unroll
      for (int nt = 0; nt < 2; ++nt)
        acc[mt][nt] = __builtin_amdgcn_mfma_f32_16x16x32_f16(hi[mt].h, bf[0][nt].h, acc[mt][nt], 0, 0, 0);
#pragma unroll
    for (int mt = 0; mt < 4; ++mt)
#pragma unroll
      for (int nt = 0; nt < 2; ++nt)
        acc[mt][nt] = __builtin_amdgcn_mfma_f32_16x16x32_f16(hj[mt].h, bf[1][nt].h, acc[mt][nt], 0, 0, 0);
    // build a2=|hi-hj|, a3=hi*hj with packed fp16 (3 VALU/word), MFMA s=2,3
#pragma unroll
    for (int mt = 0; mt < 4; ++mt) {
      const unsigned hw[4] = {hi[mt].u.x, hi[mt].u.y, hi[mt].u.z, hi[mt].u.w};
      const unsigned jw[4] = {hj[mt].u.x, hj[mt].u.y, hj[mt].u.z, hj[mt].u.w};
      unsigned d[4], pr[4];
#pragma unroll
      for (int w = 0; w < 4; ++w) {
        U32 hx, jx, dd, pp;
        hx.u = hw[w];
        jx.u = jw[w];
        dd.p = hx.p - jx.p;            // v_pk_add_f16 (neg mod)
        d[w] = dd.u & 0x7fff7fffu;     // abs: clear sign bits (exact)
        pp.p = hx.p * jx.p;            // v_pk_mul_f16
        pr[w] = pp.u;
      }
      V16 a2, a3;
      a2.u = make_uint4(d[0], d[1], d[2], d[3]);
      a3.u = make_uint4(pr[0], pr[1], pr[2], pr[3]);
#pragma unroll
      for (int nt = 0; nt < 2; ++nt)
        acc[mt][nt] = __builtin_amdgcn_mfma_f32_16x16x32_f16(a2.h, bf[2][nt].h, acc[mt][nt], 0, 0, 0);
#pragma unroll
      for (int nt = 0; nt < 2; ++nt)
        acc[mt][nt] = __builtin_amdgcn_mfma_f32_16x16x32_f16(a3.h, bf[3][nt].h, acc[mt][nt], 0, 0, 0);
    }
    w1s += 131072;
  };

  stage_chunk(0);
  __syncthreads();
#pragma unroll 2
  for (int st4 = 0; st4 < 4; ++st4) kstep(st4);

  __syncthreads();       // all reads of chunk 0 done
  stage_chunk(1);
  __syncthreads();       // chunk 1 visible (compiler drains vmcnt here)
#pragma unroll 2
  for (int st4 = 0; st4 < 4; ++st4) kstep(st4);

  // ---- epilogue: bias + ReLU + W2, 16-lane shuffle reduce, atomic out ----
#pragma unroll
  for (int mt = 0; mt < 4; ++mt) {
    float pc0[4] = {0.f, 0.f, 0.f, 0.f};
    float pc1[4] = {0.f, 0.f, 0.f, 0.f};
#pragma unroll
    for (int nt = 0; nt < 2; ++nt) {
      int gc = n0 + nt * 16 + l16;
      float b1v = b1[gc];
      float w20 = w2[gc * 2 + 0];
      float w21 = w2[gc * 2 + 1];
#pragma unroll
      for (int r = 0; r < 4; ++r) {
        float v = fmaxf(acc[mt][nt][r] + b1v, 0.f);
        pc0[r] = fmaf(v, w20, pc0[r]);
        pc1[r] = fmaf(v, w21, pc1[r]);
      }
    }
#pragma unroll
    for (int r = 0; r < 4; ++r) {
      float s0 = pc0[r], s1 = pc1[r];
#pragma unroll
      for (int off = 1; off < 16; off <<= 1) {
        s0 += __shfl_xor(s0, off);
        s1 += __shfl_xor(s1, off);
      }
      int e = row0 + mt * 16 + quad * 4 + r;  // C/D: row = quad*4 + r
      if (l16 == 0) unsafeAtomicAdd(&out[(size_t)e * 2 + 0], s0);
      if (l16 == 1) unsafeAtomicAdd(&out[(size_t)e * 2 + 1], s1);
    }
  }
}

extern "C" void kernel_launch(void* const* d_in, const int* in_sizes, int n_in,
                              void* d_out, int out_size, void* d_ws, size_t ws_size,
                              hipStream_t stream) {
  const float* node = (const float*)d_in[0];
  const int* src = (const int*)d_in[1];
  const int* dst = (const int*)d_in[2];
  const float* W1 = (const float*)d_in[3];
  const float* b1 = (const float*)d_in[4];
  const float* W2 = (const float*)d_in[5];
  const float* b2 = (const float*)d_in[6];
  float* out = (float*)d_out;

  unsigned short* nodeb = (unsigned short*)d_ws;                      // 25,600,000 B
  unsigned short* w1pp2 = (unsigned short*)((char*)d_ws + 25600000);  // 1,048,576 B

  cvt_node_kernel<<<6250, 256, 0, stream>>>(node, nodeb);
  prep_w1pp2_kernel<<<256, 256, 0, stream>>>(W1, w1pp2);
  init_out_kernel<<<1024, 256, 0, stream>>>(out, b2);
  edge_mlp_kernel<<<16384, 256, 0, stream>>>(nodeb, w1pp2, src, dst, b1, W2, out);
}

// Round 8
// 433.033 us; speedup vs baseline: 1.2293x; 1.2293x over previous
//
#include <hip/hip_runtime.h>

#define N_NODES 50000
#define E_EDGES 262144

typedef __attribute__((ext_vector_type(8))) _Float16 f16x8;
typedef __attribute__((ext_vector_type(2))) _Float16 f16x2;
typedef __attribute__((ext_vector_type(4))) float f32x4;

union V16 { uint4 u; f16x8 h; };
union U32 { unsigned u; f16x2 p; };

// pack two f32 -> two f16 (RNE), a in low half
__device__ __forceinline__ unsigned h2pack(float a, float b) {
  union { _Float16 h[2]; unsigned u; } r;
  r.h[0] = (_Float16)a;
  r.h[1] = (_Float16)b;
  return r.u;
}
__device__ __forceinline__ void async_gather16(const void* gptr, void* lptr) {
  __builtin_amdgcn_global_load_lds(
      (const __attribute__((address_space(1))) void*)gptr,
      (__attribute__((address_space(3))) void*)lptr, 16, 0, 0);
}

// ---- prep: node_repr fp32 -> fp16 (RNE) ----
__global__ void cvt_node_kernel(const float* __restrict__ x, unsigned short* __restrict__ y) {
  int i = (blockIdx.x * 256 + threadIdx.x) * 8;
  float4 f0 = *(const float4*)(x + i);
  float4 f1 = *(const float4*)(x + i + 4);
  uint4 o;
  o.x = h2pack(f0.x, f0.y);
  o.y = h2pack(f0.z, f0.w);
  o.z = h2pack(f1.x, f1.y);
  o.w = h2pack(f1.z, f1.w);
  *(uint4*)(y + i) = o;
}

// ---- prep: W1 (1024x512 row-major in->out) -> W1pp2 fp16, 16-B units laid out
// [step(8)][sq=s*4+quad(16)][col(512)], unit = W1[k0..k0+8)[col], k0=s*256+step*32+quad*8
__global__ void prep_w1pp2_kernel(const float* __restrict__ w1, unsigned short* __restrict__ w1pp2) {
  int t = blockIdx.x * 256 + threadIdx.x;  // 65536 units
  int step = t >> 13;
  int rem = t & 8191;
  int sq = rem >> 9;
  int col = rem & 511;
  int s = sq >> 2, qd = sq & 3;
  int k0 = s * 256 + step * 32 + qd * 8;
  float f[8];
#pragma unroll
  for (int i = 0; i < 8; ++i) f[i] = w1[(size_t)(k0 + i) * 512 + col];
  uint4 o;
  o.x = h2pack(f[0], f[1]);
  o.y = h2pack(f[2], f[3]);
  o.z = h2pack(f[4], f[5]);
  o.w = h2pack(f[6], f[7]);
  *(uint4*)(w1pp2 + (size_t)t * 8) = o;
}

// ---- prep: out[e][c] = b2[c] ----
__global__ void init_out_kernel(float* __restrict__ out, const float* __restrict__ b2) {
  int i = blockIdx.x * 256 + threadIdx.x;
  float2 v; v.x = b2[0]; v.y = b2[1];
  *(float2*)(out + (size_t)i * 2) = v;
}

// ---- main fused kernel R8: block = 64 edges x 512 cols (8 waves), wave = 64e x 64c
//      (the PROVEN efficient tile), f16 datapath (92 VGPR in R5). ONE barrier.
//      WHY: R7 proved occupancy rises when total regs (VGPR+acc) allow, but its
//      64x32 wave tile halved MFMA amortization and regressed. This block shape
//      gains occupancy WITHOUT shrinking the wave tile: LDS 64KB -> 2 blocks/CU
//      = 16 waves/CU = 4/SIMD possible; reg pool 512/SIMD / ~156 -> 3/SIMD (vs 2
//      today). Also: each edge-tile gathered ONCE (FETCH halves).
//      CRITICAL: no second __launch_bounds__ arg — (512,4) and (256,4) both
//      forced VGPR=64 -> 5.5 GB scratch spill -> 5x regression (R1/R3). ----
__global__ __launch_bounds__(512) void edge_mlp_kernel(
    const unsigned short* __restrict__ nodeb,  // [50000][256] fp16
    const unsigned short* __restrict__ w1pp2,  // repacked W1 (see prep)
    const int* __restrict__ src,
    const int* __restrict__ dst,
    const float* __restrict__ b1,
    const float* __restrict__ w2,   // [512][2] fp32
    float* __restrict__ out) {      // [E][2] fp32, pre-init with b2
  // hi: [0,32K) — 64 edges x 512 B; hj: [32K,64K)
  // 16-B unit slot for (e, st, q): e*32 + ((st*4+q) ^ (e&7))
  __shared__ char smem[65536];

  const int tid = threadIdx.x;
  const int wid = tid >> 6;      // 0..7 -> 8 waves x 64 cols = all 512 cols
  const int lane = tid & 63;
  const int quad = lane >> 4;
  const int l16 = lane & 15;
  const int bx = blockIdx.x;     // 0..4095
  // XCD swizzle: xc = bx&7; neighbor m-tiles share an XCD
  const int xc = bx & 7;
  const int m_idx = (bx >> 3) * 8 + xc;      // 0..4095 (64-edge tiles)
  const int row0 = m_idx * 64;
  const int n0 = wid * 64;

  const char* nodeB = (const char*)nodeb;
  const char* w1B = (const char*)w1pp2;

  // ---- B register-load offsets: (s*4+quad)*8192 + (n0+l16)*16 (+ step*131072) ----
  unsigned bOff[4];
#pragma unroll
  for (int s = 0; s < 4; ++s)
    bOff[s] = (unsigned)((s * 4 + quad) * 8192 + (n0 + l16) * 16);
  const char* w1s = w1B;

  // ---- A reader base: byte = (mt*16+l16)*512 + (((st*4+q)^(l16&7))<<4) ----
  const unsigned aXor = (unsigned)(l16 & 7);
  const unsigned aBase = (unsigned)(l16 * 512);

  f32x4 acc[4][4];
#pragma unroll
  for (int mt = 0; mt < 4; ++mt)
#pragma unroll
    for (int nt = 0; nt < 4; ++nt)
      acc[mt][nt] = (f32x4){0.f, 0.f, 0.f, 0.f};

  // ---- prologue: stage ALL of A (hi+hj, 64 edges x 512 B each region) ----
  // call c stages slots v = c*512+tid; e = v>>5 = c*16 + (tid>>5); w = tid&31
  // dst byte = v*16 = c*8192 + wid*1024 + lane*16 (linear); source carries the
  // XOR swizzle: unit u = w ^ (e&7). e&7 == (tid>>5)&7 since c*16 ≡ 0 (mod 8).
  {
    const int eh = tid >> 5;                                        // 0..15
    const unsigned wsw = (unsigned)(((tid & 31) ^ (eh & 7)) << 4);
#pragma unroll
    for (int c = 0; c < 4; ++c) {
      int e = c * 16 + eh;
      unsigned so = ((unsigned)src[row0 + e] << 9) + wsw;
      unsigned do_ = ((unsigned)dst[row0 + e] << 9) + wsw;
      async_gather16(nodeB + so, smem + c * 8192 + wid * 1024);
      async_gather16(nodeB + do_, smem + 32768 + c * 8192 + wid * 1024);
    }
  }
  __syncthreads();  // the ONLY barrier

#pragma unroll 2
  for (int step = 0; step < 8; ++step) {
    // B(t) loads — compiler emits fine-grained vmcnt; with unroll-2, B(t+1) overlaps MFMAs
    V16 bf[4][4];
#pragma unroll
    for (int s = 0; s < 4; ++s)
#pragma unroll
      for (int nt = 0; nt < 4; ++nt)
        bf[s][nt].u = *(const uint4*)(w1s + bOff[s] + nt * 256);
    // A fragments from LDS (read-only, no sync needed)
    const unsigned stq = (unsigned)(step * 4 + quad);
    V16 hi[4], hj[4];
#pragma unroll
    for (int mt = 0; mt < 4; ++mt) {
      unsigned ao = (unsigned)(mt * 16 * 512) + aBase + ((stq ^ aXor) << 4);
      hi[mt].u = *(const uint4*)(smem + ao);
      hj[mt].u = *(const uint4*)(smem + 32768 + ao);
    }
    // MFMA s=0 (hi), s=1 (hj)
#pragma unroll
    for (int mt = 0; mt < 4; ++mt)
#pragma unroll
      for (int nt = 0; nt < 4; ++nt)
        acc[mt][nt] = __builtin_amdgcn_mfma_f32_16x16x32_f16(hi[mt].h, bf[0][nt].h, acc[mt][nt], 0, 0, 0);
#pragma unroll
    for (int mt = 0; mt < 4; ++mt)
#pragma unroll
      for (int nt = 0; nt < 4; ++nt)
        acc[mt][nt] = __builtin_amdgcn_mfma_f32_16x16x32_f16(hj[mt].h, bf[1][nt].h, acc[mt][nt], 0, 0, 0);
    // build a2=|hi-hj|, a3=hi*hj with packed fp16 (3 VALU/word), MFMA s=2,3
#pragma unroll
    for (int mt = 0; mt < 4; ++mt) {
      const unsigned hw[4] = {hi[mt].u.x, hi[mt].u.y, hi[mt].u.z, hi[mt].u.w};
      const unsigned jw[4] = {hj[mt].u.x, hj[mt].u.y, hj[mt].u.z, hj[mt].u.w};
      unsigned d[4], pr[4];
#pragma unroll
      for (int w = 0; w < 4; ++w) {
        U32 hx, jx, dd, pp;
        hx.u = hw[w];
        jx.u = jw[w];
        dd.p = hx.p - jx.p;            // v_pk_add_f16 (neg mod)
        d[w] = dd.u & 0x7fff7fffu;     // abs: clear sign bits (exact)
        pp.p = hx.p * jx.p;            // v_pk_mul_f16
        pr[w] = pp.u;
      }
      V16 a2, a3;
      a2.u = make_uint4(d[0], d[1], d[2], d[3]);
      a3.u = make_uint4(pr[0], pr[1], pr[2], pr[3]);
#pragma unroll
      for (int nt = 0; nt < 4; ++nt)
        acc[mt][nt] = __builtin_amdgcn_mfma_f32_16x16x32_f16(a2.h, bf[2][nt].h, acc[mt][nt], 0, 0, 0);
#pragma unroll
      for (int nt = 0; nt < 4; ++nt)
        acc[mt][nt] = __builtin_amdgcn_mfma_f32_16x16x32_f16(a3.h, bf[3][nt].h, acc[mt][nt], 0, 0, 0);
    }
    w1s += 131072;
  }

  // ---- epilogue: bias + ReLU + W2, 16-lane shuffle reduce, atomic out ----
#pragma unroll
  for (int mt = 0; mt < 4; ++mt) {
    float pc0[4] = {0.f, 0.f, 0.f, 0.f};
    float pc1[4] = {0.f, 0.f, 0.f, 0.f};
#pragma unroll
    for (int nt = 0; nt < 4; ++nt) {
      int gc = n0 + nt * 16 + l16;
      float b1v = b1[gc];
      float w20 = w2[gc * 2 + 0];
      float w21 = w2[gc * 2 + 1];
#pragma unroll
      for (int r = 0; r < 4; ++r) {
        float v = fmaxf(acc[mt][nt][r] + b1v, 0.f);
        pc0[r] = fmaf(v, w20, pc0[r]);
        pc1[r] = fmaf(v, w21, pc1[r]);
      }
    }
#pragma unroll
    for (int r = 0; r < 4; ++r) {
      float s0 = pc0[r], s1 = pc1[r];
#pragma unroll
      for (int off = 1; off < 16; off <<= 1) {
        s0 += __shfl_xor(s0, off);
        s1 += __shfl_xor(s1, off);
      }
      int e = row0 + mt * 16 + quad * 4 + r;  // C/D: row = quad*4 + r
      if (l16 == 0) unsafeAtomicAdd(&out[(size_t)e * 2 + 0], s0);
      if (l16 == 1) unsafeAtomicAdd(&out[(size_t)e * 2 + 1], s1);
    }
  }
}

extern "C" void kernel_launch(void* const* d_in, const int* in_sizes, int n_in,
                              void* d_out, int out_size, void* d_ws, size_t ws_size,
                              hipStream_t stream) {
  const float* node = (const float*)d_in[0];
  const int* src = (const int*)d_in[1];
  const int* dst = (const int*)d_in[2];
  const float* W1 = (const float*)d_in[3];
  const float* b1 = (const float*)d_in[4];
  const float* W2 = (const float*)d_in[5];
  const float* b2 = (const float*)d_in[6];
  float* out = (float*)d_out;

  unsigned short* nodeb = (unsigned short*)d_ws;                      // 25,600,000 B
  unsigned short* w1pp2 = (unsigned short*)((char*)d_ws + 25600000);  // 1,048,576 B

  cvt_node_kernel<<<6250, 256, 0, stream>>>(node, nodeb);
  prep_w1pp2_kernel<<<256, 256, 0, stream>>>(W1, w1pp2);
  init_out_kernel<<<1024, 256, 0, stream>>>(out, b2);
  edge_mlp_kernel<<<4096, 512, 0, stream>>>(nodeb, w1pp2, src, dst, b1, W2, out);
}

// Round 9
// 417.809 us; speedup vs baseline: 1.2741x; 1.0364x over previous
//
#include <hip/hip_runtime.h>

#define N_NODES 50000
#define E_EDGES 262144

typedef __attribute__((ext_vector_type(8))) _Float16 f16x8;
typedef __attribute__((ext_vector_type(2))) _Float16 f16x2;
typedef __attribute__((ext_vector_type(4))) float f32x4;

union V16 { uint4 u; f16x8 h; };
union U32 { unsigned u; f16x2 p; };

// pack two f32 -> two f16 (RNE), a in low half
__device__ __forceinline__ unsigned h2pack(float a, float b) {
  union { _Float16 h[2]; unsigned u; } r;
  r.h[0] = (_Float16)a;
  r.h[1] = (_Float16)b;
  return r.u;
}
__device__ __forceinline__ void async_gather16(const void* gptr, void* lptr) {
  __builtin_amdgcn_global_load_lds(
      (const __attribute__((address_space(1))) void*)gptr,
      (__attribute__((address_space(3))) void*)lptr, 16, 0, 0);
}

// ---- prep: node_repr fp32 -> fp16 (RNE) ----
__global__ void cvt_node_kernel(const float* __restrict__ x, unsigned short* __restrict__ y) {
  int i = (blockIdx.x * 256 + threadIdx.x) * 8;
  float4 f0 = *(const float4*)(x + i);
  float4 f1 = *(const float4*)(x + i + 4);
  uint4 o;
  o.x = h2pack(f0.x, f0.y);
  o.y = h2pack(f0.z, f0.w);
  o.z = h2pack(f1.x, f1.y);
  o.w = h2pack(f1.z, f1.w);
  *(uint4*)(y + i) = o;
}

// ---- prep: W1 (1024x512 row-major in->out) -> W1pp2 fp16, 16-B units laid out
// [step(8)][sq=s*4+quad(16)][col(512)], unit = W1[k0..k0+8)[col], k0=s*256+step*32+quad*8
__global__ void prep_w1pp2_kernel(const float* __restrict__ w1, unsigned short* __restrict__ w1pp2) {
  int t = blockIdx.x * 256 + threadIdx.x;  // 65536 units
  int step = t >> 13;
  int rem = t & 8191;
  int sq = rem >> 9;
  int col = rem & 511;
  int s = sq >> 2, qd = sq & 3;
  int k0 = s * 256 + step * 32 + qd * 8;
  float f[8];
#pragma unroll
  for (int i = 0; i < 8; ++i) f[i] = w1[(size_t)(k0 + i) * 512 + col];
  uint4 o;
  o.x = h2pack(f[0], f[1]);
  o.y = h2pack(f[2], f[3]);
  o.z = h2pack(f[4], f[5]);
  o.w = h2pack(f[6], f[7]);
  *(uint4*)(w1pp2 + (size_t)t * 8) = o;
}

// ---- prep: out[e][c] = b2[c] ----
__global__ void init_out_kernel(float* __restrict__ out, const float* __restrict__ b2) {
  int i = blockIdx.x * 256 + threadIdx.x;
  float2 v; v.x = b2[0]; v.y = b2[1];
  *(float2*)(out + (size_t)i * 2) = v;
}

// ---- main fused kernel R9: block = 64 edges x 512 cols (8 waves), wave = 64e x 64c.
//      R8 measured: arch VGPR=68 + acc AGPR=64 = 132 total -> 4 over the 128
//      occupancy boundary -> 2 waves/SIMD (Occ 23.7%). This round forces the
//      boundary: __launch_bounds__(512,2) = the empirically-calibrated 128/wave
//      budget (R2), plus source shave: bOff[4] (4 persistent VGPRs) collapsed to
//      one bQ reg with compile-time s*32768+nt*256 addends. Target: arch 64 +
//      acc 64 = 128 -> 4 waves/SIMD (16 waves/CU; LDS 2x64KB=128<=160 OK).
//      SPILL GATE: if WRITE_SIZE > 131 MB the squeeze failed (R2-style spill). ----
__global__ __launch_bounds__(512, 2) void edge_mlp_kernel(
    const unsigned short* __restrict__ nodeb,  // [50000][256] fp16
    const unsigned short* __restrict__ w1pp2,  // repacked W1 (see prep)
    const int* __restrict__ src,
    const int* __restrict__ dst,
    const float* __restrict__ b1,
    const float* __restrict__ w2,   // [512][2] fp32
    float* __restrict__ out) {      // [E][2] fp32, pre-init with b2
  // hi: [0,32K) — 64 edges x 512 B; hj: [32K,64K)
  // 16-B unit slot for (e, st, q): e*32 + ((st*4+q) ^ (e&7))
  __shared__ char smem[65536];

  const int tid = threadIdx.x;
  const int wid = tid >> 6;      // 0..7 -> 8 waves x 64 cols = all 512 cols
  const int lane = tid & 63;
  const int quad = lane >> 4;
  const int l16 = lane & 15;
  const int bx = blockIdx.x;     // 0..4095
  // XCD swizzle: xc = bx&7; neighbor m-tiles share an XCD
  const int xc = bx & 7;
  const int m_idx = (bx >> 3) * 8 + xc;      // 0..4095 (64-edge tiles)
  const int row0 = m_idx * 64;
  const int n0 = wid * 64;

  const char* nodeB = (const char*)nodeb;
  const char* w1B = (const char*)w1pp2;

  // ---- B load base: ONE persistent VGPR; s/nt offsets are compile-time.
  //      byte(s,nt,step) = bQ + s*32768 + nt*256 + step*131072 ----
  const unsigned bQ = (unsigned)(quad * 8192 + (n0 + l16) * 16);
  const char* w1s = w1B;

  // ---- A reader base: byte = (mt*16+l16)*512 + (((st*4+q)^(l16&7))<<4) ----
  const unsigned aXor = (unsigned)(l16 & 7);
  const unsigned aBase = (unsigned)(l16 * 512);

  f32x4 acc[4][4];
#pragma unroll
  for (int mt = 0; mt < 4; ++mt)
#pragma unroll
    for (int nt = 0; nt < 4; ++nt)
      acc[mt][nt] = (f32x4){0.f, 0.f, 0.f, 0.f};

  // ---- prologue: stage ALL of A (hi+hj, 64 edges x 512 B each region) ----
  // call c stages slots v = c*512+tid; e = v>>5 = c*16 + (tid>>5); w = tid&31
  // dst byte = v*16 (linear); source carries the XOR swizzle u = w ^ (e&7).
  {
    const int eh = tid >> 5;                                        // 0..15
    const unsigned wsw = (unsigned)(((tid & 31) ^ (eh & 7)) << 4);
#pragma unroll
    for (int c = 0; c < 4; ++c) {
      int e = c * 16 + eh;
      unsigned so = ((unsigned)src[row0 + e] << 9) + wsw;
      unsigned do_ = ((unsigned)dst[row0 + e] << 9) + wsw;
      async_gather16(nodeB + so, smem + c * 8192 + wid * 1024);
      async_gather16(nodeB + do_, smem + 32768 + c * 8192 + wid * 1024);
    }
  }
  __syncthreads();  // the ONLY barrier

#pragma unroll 2
  for (int step = 0; step < 8; ++step) {
    // B(t) loads — compiler emits fine-grained vmcnt and serializes to fit regs
    V16 bf[4][4];
#pragma unroll
    for (int s = 0; s < 4; ++s)
#pragma unroll
      for (int nt = 0; nt < 4; ++nt)
        bf[s][nt].u = *(const uint4*)(w1s + (bQ + (unsigned)(s * 32768 + nt * 256)));
    // A fragments from LDS (read-only, no sync needed)
    const unsigned stq = (unsigned)(step * 4 + quad);
    V16 hi[4], hj[4];
#pragma unroll
    for (int mt = 0; mt < 4; ++mt) {
      unsigned ao = (unsigned)(mt * 16 * 512) + aBase + ((stq ^ aXor) << 4);
      hi[mt].u = *(const uint4*)(smem + ao);
      hj[mt].u = *(const uint4*)(smem + 32768 + ao);
    }
    // MFMA s=0 (hi), s=1 (hj)
#pragma unroll
    for (int mt = 0; mt < 4; ++mt)
#pragma unroll
      for (int nt = 0; nt < 4; ++nt)
        acc[mt][nt] = __builtin_amdgcn_mfma_f32_16x16x32_f16(hi[mt].h, bf[0][nt].h, acc[mt][nt], 0, 0, 0);
#pragma unroll
    for (int mt = 0; mt < 4; ++mt)
#pragma unroll
      for (int nt = 0; nt < 4; ++nt)
        acc[mt][nt] = __builtin_amdgcn_mfma_f32_16x16x32_f16(hj[mt].h, bf[1][nt].h, acc[mt][nt], 0, 0, 0);
    // build a2=|hi-hj|, a3=hi*hj with packed fp16 (3 VALU/word), MFMA s=2,3
#pragma unroll
    for (int mt = 0; mt < 4; ++mt) {
      const unsigned hw[4] = {hi[mt].u.x, hi[mt].u.y, hi[mt].u.z, hi[mt].u.w};
      const unsigned jw[4] = {hj[mt].u.x, hj[mt].u.y, hj[mt].u.z, hj[mt].u.w};
      unsigned d[4], pr[4];
#pragma unroll
      for (int w = 0; w < 4; ++w) {
        U32 hx, jx, dd, pp;
        hx.u = hw[w];
        jx.u = jw[w];
        dd.p = hx.p - jx.p;            // v_pk_add_f16 (neg mod)
        d[w] = dd.u & 0x7fff7fffu;     // abs: clear sign bits (exact)
        pp.p = hx.p * jx.p;            // v_pk_mul_f16
        pr[w] = pp.u;
      }
      V16 a2, a3;
      a2.u = make_uint4(d[0], d[1], d[2], d[3]);
      a3.u = make_uint4(pr[0], pr[1], pr[2], pr[3]);
#pragma unroll
      for (int nt = 0; nt < 4; ++nt)
        acc[mt][nt] = __builtin_amdgcn_mfma_f32_16x16x32_f16(a2.h, bf[2][nt].h, acc[mt][nt], 0, 0, 0);
#pragma unroll
      for (int nt = 0; nt < 4; ++nt)
        acc[mt][nt] = __builtin_amdgcn_mfma_f32_16x16x32_f16(a3.h, bf[3][nt].h, acc[mt][nt], 0, 0, 0);
    }
    w1s += 131072;
  }

  // ---- epilogue: bias + ReLU + W2, 16-lane shuffle reduce, atomic out ----
#pragma unroll
  for (int mt = 0; mt < 4; ++mt) {
    float pc0[4] = {0.f, 0.f, 0.f, 0.f};
    float pc1[4] = {0.f, 0.f, 0.f, 0.f};
#pragma unroll
    for (int nt = 0; nt < 4; ++nt) {
      int gc = n0 + nt * 16 + l16;
      float b1v = b1[gc];
      float w20 = w2[gc * 2 + 0];
      float w21 = w2[gc * 2 + 1];
#pragma unroll
      for (int r = 0; r < 4; ++r) {
        float v = fmaxf(acc[mt][nt][r] + b1v, 0.f);
        pc0[r] = fmaf(v, w20, pc0[r]);
        pc1[r] = fmaf(v, w21, pc1[r]);
      }
    }
#pragma unroll
    for (int r = 0; r < 4; ++r) {
      float s0 = pc0[r], s1 = pc1[r];
#pragma unroll
      for (int off = 1; off < 16; off <<= 1) {
        s0 += __shfl_xor(s0, off);
        s1 += __shfl_xor(s1, off);
      }
      int e = row0 + mt * 16 + quad * 4 + r;  // C/D: row = quad*4 + r
      if (l16 == 0) unsafeAtomicAdd(&out[(size_t)e * 2 + 0], s0);
      if (l16 == 1) unsafeAtomicAdd(&out[(size_t)e * 2 + 1], s1);
    }
  }
}

extern "C" void kernel_launch(void* const* d_in, const int* in_sizes, int n_in,
                              void* d_out, int out_size, void* d_ws, size_t ws_size,
                              hipStream_t stream) {
  const float* node = (const float*)d_in[0];
  const int* src = (const int*)d_in[1];
  const int* dst = (const int*)d_in[2];
  const float* W1 = (const float*)d_in[3];
  const float* b1 = (const float*)d_in[4];
  const float* W2 = (const float*)d_in[5];
  const float* b2 = (const float*)d_in[6];
  float* out = (float*)d_out;

  unsigned short* nodeb = (unsigned short*)d_ws;                      // 25,600,000 B
  unsigned short* w1pp2 = (unsigned short*)((char*)d_ws + 25600000);  // 1,048,576 B

  cvt_node_kernel<<<6250, 256, 0, stream>>>(node, nodeb);
  prep_w1pp2_kernel<<<256, 256, 0, stream>>>(W1, w1pp2);
  init_out_kernel<<<1024, 256, 0, stream>>>(out, b2);
  edge_mlp_kernel<<<4096, 512, 0, stream>>>(nodeb, w1pp2, src, dst, b1, W2, out);
}